// Round 15
// baseline (260.904 us; speedup 1.0000x reference)
//
#include <hip/hip_runtime.h>
#include <hip/hip_fp16.h>

#define NNODES 100000
#define NEDGES 1600000
#define DIM    128
#define NEG_SLOPE 0.01f
#define NB_SCAN ((NNODES + 1023) / 1024)   // 98 blocks of 1024 counts
// mid-path (8-part) macros
#define NPART 8
#define PART_SZ ((NNODES + NPART - 1) / NPART)   // 12500
// full-path: 64 sub-parts; sp & 7 = XCD class (blocks for sp have b%8 == sp%8)
#define NSUB 64
#define SUB_SZ ((NNODES + NSUB - 1) / NSUB)      // 1563 (11 bits)
#define SCAP 27000                                // per-sub-part cap (exp 25000, ~13 sigma)
#define SCUR_STRIDE 32                            // pad counters to 128B
#define CHUNK 2048                                // edges per split block (8/thread)
#define GEMM_TILES ((NNODES + 63) / 64)           // 1563

typedef _Float16     v8h __attribute__((ext_vector_type(8)));
typedef float        v4f __attribute__((ext_vector_type(4)));
typedef int          v4i __attribute__((ext_vector_type(4)));
typedef int          v2i __attribute__((ext_vector_type(2)));
typedef float        v4x __attribute__((ext_vector_type(4)));
typedef unsigned int v2u __attribute__((ext_vector_type(2)));
typedef unsigned int v4u __attribute__((ext_vector_type(4)));

static inline size_t align256(size_t x) { return (x + 255) & ~(size_t)255; }

union HU { unsigned int u; __half2 h; };
union U4H { uint4 u; __half2 h[4]; };

// ---------------- zero (fallback) ----------------
__global__ __launch_bounds__(256) void zero_f32(float* __restrict__ p, int n4) {
    int i = blockIdx.x * blockDim.x + threadIdx.x;
    int stride = gridDim.x * blockDim.x;
    float4 z = make_float4(0.f, 0.f, 0.f, 0.f);
    for (; i < n4; i += stride) ((float4*)p)[i] = z;
}

// ---- prep: converts + zero counts/scur (R13-proven) ----
__global__ __launch_bounds__(256) void prep(const float* __restrict__ nf,
                                            const float* __restrict__ W,
                                            __half* __restrict__ nf16,
                                            __half* __restrict__ W16,
                                            int* __restrict__ counts,
                                            int* __restrict__ scur) {
    int i = blockIdx.x * 256 + threadIdx.x;
    int stride = gridDim.x * 256;
    for (int j = i; j < NNODES * DIM / 4; j += stride) {
        v4x v = __builtin_nontemporal_load((const v4x*)nf + j);
        HU a, b;
        a.h = __float22half2_rn(make_float2(v.x, v.y));
        b.h = __float22half2_rn(make_float2(v.z, v.w));
        ((uint2*)nf16)[j] = make_uint2(a.u, b.u);
    }
    const float4* Wg4 = (const float4*)W;
    for (int j = i; j < DIM * DIM / 8; j += stride) {
        float4 lo = Wg4[j * 2], hi = Wg4[j * 2 + 1];
        HU a, b, c, d;
        a.h = __float22half2_rn(make_float2(lo.x, lo.y));
        b.h = __float22half2_rn(make_float2(lo.z, lo.w));
        c.h = __float22half2_rn(make_float2(hi.x, hi.y));
        d.h = __float22half2_rn(make_float2(hi.z, hi.w));
        ((uint4*)W16)[j] = make_uint4(a.u, b.u, c.u, d.u);
    }
    v4i z = (v4i){0, 0, 0, 0};
    for (int j = i; j < NNODES / 4; j += stride)
        *((v4i*)counts + j) = z;
    if (i < NSUB * SCUR_STRIDE) scur[i] = 0;
}

// ---- pass A: 64-way split, 8 edges/thread, per-wave LDS-atomic rank (R13) ----
__global__ __launch_bounds__(256) void split_edges(const int* __restrict__ esrc,
                                                   const int* __restrict__ edst,
                                                   const float* __restrict__ ew,
                                                   int* __restrict__ scur,
                                                   int2* __restrict__ pairs) {
    __shared__ int wcnt[4][NSUB];
    __shared__ int wbase[4][NSUB];
    __shared__ int gbase[NSUB];
    int tid = threadIdx.x;
    int wave = tid >> 6;
    ((int*)wcnt)[tid] = 0;            // 4*64 == 256
    __syncthreads();

    int nq = NEDGES / 4;
    int qA = blockIdx.x * (CHUNK / 4) + tid;
    int qB = qA + 256;

    v4i dA = (v4i){0,0,0,0}, sA = (v4i){0,0,0,0};
    v4x wA = (v4x){0,0,0,0};
    v4i dB = (v4i){0,0,0,0}, sB = (v4i){0,0,0,0};
    v4x wB = (v4x){0,0,0,0};
    bool vA = qA < nq, vB = qB < nq;
    if (vA) {
        dA = __builtin_nontemporal_load((const v4i*)edst + qA);
        sA = __builtin_nontemporal_load((const v4i*)esrc + qA);
        wA = __builtin_nontemporal_load((const v4x*)ew + qA);
    }
    if (vB) {
        dB = __builtin_nontemporal_load((const v4i*)edst + qB);
        sB = __builtin_nontemporal_load((const v4i*)esrc + qB);
        wB = __builtin_nontemporal_load((const v4x*)ew + qB);
    }

    int sp8[8]; int rnk[8]; int2 pv[8];
    #pragma unroll
    for (int k = 0; k < 4; ++k) {
        int d = dA[k], s = sA[k];
        int p = vA ? (int)((unsigned)d / SUB_SZ) : -1;
        sp8[k] = p;
        pv[k] = make_int2(((d - p * SUB_SZ) << 17) | s, __float_as_int(wA[k]));
        int d2 = dB[k], s2 = sB[k];
        int p2 = vB ? (int)((unsigned)d2 / SUB_SZ) : -1;
        sp8[k + 4] = p2;
        pv[k + 4] = make_int2(((d2 - p2 * SUB_SZ) << 17) | s2, __float_as_int(wB[k]));
    }

    #pragma unroll
    for (int s = 0; s < 8; ++s) {
        if (sp8[s] >= 0)
            rnk[s] = atomicAdd(&wcnt[wave][sp8[s]], 1);   // avg 1 lane/bucket
    }
    __syncthreads();
    if (tid < NSUB) {
        int t0 = wcnt[0][tid], t1 = wcnt[1][tid], t2 = wcnt[2][tid], t3 = wcnt[3][tid];
        wbase[0][tid] = 0; wbase[1][tid] = t0;
        wbase[2][tid] = t0 + t1; wbase[3][tid] = t0 + t1 + t2;
        gbase[tid] = atomicAdd(&scur[tid * SCUR_STRIDE], t0 + t1 + t2 + t3);
    }
    __syncthreads();

    #pragma unroll
    for (int s = 0; s < 8; ++s) {
        int p = sp8[s];
        if (p >= 0) {
            int slot = gbase[p] + wbase[wave][p] + rnk[s];
            if (slot < SCAP)
                pairs[(size_t)p * SCAP + slot] = pv[s];
        }
    }
}

// ---- pass B: per-sub-part histogram (6KB window), 4 records/iter (R13) ----
__global__ __launch_bounds__(256) void hist_part(const int2* __restrict__ pairs,
                                                 const int* __restrict__ scur,
                                                 int* __restrict__ counts) {
    int b = blockIdx.x;
    int sp = b & 63;
    int w = b >> 6;                               // 0..31
    int n = scur[sp * SCUR_STRIDE];
    if (n > SCAP) n = SCAP;
    const int2* base = pairs + (size_t)sp * SCAP;
    int cbase = sp * SUB_SZ;
    int ng = n >> 2;                              // groups of 4 records
    for (int i = w * 256 + threadIdx.x; i < ng; i += 8192) {
        v4i a = __builtin_nontemporal_load((const v4i*)base + 2 * i);
        v4i c = __builtin_nontemporal_load((const v4i*)base + 2 * i + 1);
        atomicAdd(&counts[cbase + ((unsigned)a.x >> 17)], 1);
        atomicAdd(&counts[cbase + ((unsigned)a.z >> 17)], 1);
        atomicAdd(&counts[cbase + ((unsigned)c.x >> 17)], 1);
        atomicAdd(&counts[cbase + ((unsigned)c.z >> 17)], 1);
    }
    if (w == 0 && threadIdx.x < 3) {
        int idx = (ng << 2) + threadIdx.x;
        if (idx < n) {
            int2 pr = base[idx];
            atomicAdd(&counts[cbase + ((unsigned)pr.x >> 17)], 1);
        }
    }
}

// ---- scan step 1 (R13) ----
__global__ __launch_bounds__(256) void scan1(const int* __restrict__ counts,
                                             int* __restrict__ offsets,
                                             int* __restrict__ blocksum) {
    __shared__ int lds[256];
    int tid = threadIdx.x;
    int base = blockIdx.x * 1024 + tid * 4;
    int c0 = (base + 0 < NNODES) ? counts[base + 0] : 0;
    int c1 = (base + 1 < NNODES) ? counts[base + 1] : 0;
    int c2 = (base + 2 < NNODES) ? counts[base + 2] : 0;
    int c3 = (base + 3 < NNODES) ? counts[base + 3] : 0;
    int t = c0 + c1 + c2 + c3;
    lds[tid] = t;
    __syncthreads();
    for (int d = 1; d < 256; d <<= 1) {
        int v = lds[tid];
        int add = (tid >= d) ? lds[tid - d] : 0;
        __syncthreads();
        lds[tid] = v + add;
        __syncthreads();
    }
    int incl = lds[tid];
    int excl = incl - t;
    if (base + 0 < NNODES) offsets[base + 0] = excl;
    if (base + 1 < NNODES) offsets[base + 1] = excl + c0;
    if (base + 2 < NNODES) offsets[base + 2] = excl + c0 + c1;
    if (base + 3 < NNODES) offsets[base + 3] = excl + c0 + c1 + c2;
    if (tid == 255) blocksum[blockIdx.x] = incl;
}

// ---- scan step 2 (R13) ----
__global__ __launch_bounds__(128) void scan2p(int* __restrict__ blocksum, int nb) {
    __shared__ int lds[128];
    int tid = threadIdx.x;
    int v = (tid < nb) ? blocksum[tid] : 0;
    lds[tid] = v;
    __syncthreads();
    for (int d = 1; d < 128; d <<= 1) {
        int x = lds[tid];
        int add = (tid >= d) ? lds[tid - d] : 0;
        __syncthreads();
        lds[tid] = x + add;
        __syncthreads();
    }
    if (tid < nb) blocksum[tid] = lds[tid] - v;   // exclusive
}

// ---- scan step 3: finalize offsets (doubles as fill cursor) (R13) ----
__global__ __launch_bounds__(256) void scan3(int* __restrict__ offsets,
                                             const int* __restrict__ blocksum) {
    int add = blocksum[blockIdx.x];
    int base = blockIdx.x * 1024 + threadIdx.x * 4;
    #pragma unroll
    for (int i = 0; i < 4; ++i) {
        int idx = base + i;
        if (idx < NNODES) offsets[idx] += add;
    }
}

// ---- pass C: fill bins per sub-part (~200KB dirty window, L2-resident) (R13) ----
__global__ __launch_bounds__(256) void fill_part2(const int2* __restrict__ pairs,
                                                  const int* __restrict__ scur,
                                                  int* __restrict__ offsets,
                                                  int2* __restrict__ bins) {
    int b = blockIdx.x;
    int sp = b & 63;
    int w = b >> 6;
    int n = scur[sp * SCUR_STRIDE];
    if (n > SCAP) n = SCAP;
    const int2* base = pairs + (size_t)sp * SCAP;
    int cbase = sp * SUB_SZ;
    int ng = n >> 2;
    for (int i = w * 256 + threadIdx.x; i < ng; i += 8192) {
        v4i a = __builtin_nontemporal_load((const v4i*)base + 2 * i);
        v4i c = __builtin_nontemporal_load((const v4i*)base + 2 * i + 1);
        int d0 = cbase + ((unsigned)a.x >> 17);
        int p0 = atomicAdd(&offsets[d0], 1);
        bins[p0] = make_int2(a.x & 0x1FFFF, a.y);
        int d1 = cbase + ((unsigned)a.z >> 17);
        int p1 = atomicAdd(&offsets[d1], 1);
        bins[p1] = make_int2(a.z & 0x1FFFF, a.w);
        int d2 = cbase + ((unsigned)c.x >> 17);
        int p2 = atomicAdd(&offsets[d2], 1);
        bins[p2] = make_int2(c.x & 0x1FFFF, c.y);
        int d3 = cbase + ((unsigned)c.z >> 17);
        int p3 = atomicAdd(&offsets[d3], 1);
        bins[p3] = make_int2(c.z & 0x1FFFF, c.w);
    }
    if (w == 0 && threadIdx.x < 3) {
        int idx = (ng << 2) + threadIdx.x;
        if (idx < n) {
            int2 pr = base[idx];
            int d = cbase + ((unsigned)pr.x >> 17);
            int p = atomicAdd(&offsets[d], 1);
            bins[p] = make_int2(pr.x & 0x1FFFF, pr.y);
        }
    }
}

// ---- pull: 16 lanes/node, uint4 gathers, packed-f16 accumulate (R10-proven math) ----
// offsets holds END pointer after fill; start = end - counts[v].
__global__ __launch_bounds__(256) void pull_x16(const __half* __restrict__ nf16,
                                                const int* __restrict__ offsets,
                                                const int* __restrict__ counts,
                                                const int2* __restrict__ bins,
                                                __half* __restrict__ x16) {
    int gid = blockIdx.x * 256 + threadIdx.x;
    int v = gid >> 4;
    int lane = gid & 15;
    if (v >= NNODES) return;
    int end = offsets[v];
    int start = end - counts[v];
    const uint4* nfu4 = (const uint4*)nf16;   // row = 16 uint4
    __half2 z2 = __float2half2_rn(0.f);
    U4H a0, a1, a2, a3;
    #pragma unroll
    for (int j = 0; j < 4; ++j) { a0.h[j] = z2; a1.h[j] = z2; a2.h[j] = z2; a3.h[j] = z2; }
    int k = start;
    for (; k + 4 <= end; k += 4) {
        v2i e0 = __builtin_nontemporal_load((const v2i*)bins + k);
        v2i e1 = __builtin_nontemporal_load((const v2i*)bins + k + 1);
        v2i e2 = __builtin_nontemporal_load((const v2i*)bins + k + 2);
        v2i e3 = __builtin_nontemporal_load((const v2i*)bins + k + 3);
        U4H u0, u1, u2, u3;
        u0.u = nfu4[(size_t)e0.x * 16 + lane];
        u1.u = nfu4[(size_t)e1.x * 16 + lane];
        u2.u = nfu4[(size_t)e2.x * 16 + lane];
        u3.u = nfu4[(size_t)e3.x * 16 + lane];
        __half2 w0 = __float2half2_rn(__int_as_float(e0.y));
        __half2 w1 = __float2half2_rn(__int_as_float(e1.y));
        __half2 w2 = __float2half2_rn(__int_as_float(e2.y));
        __half2 w3 = __float2half2_rn(__int_as_float(e3.y));
        #pragma unroll
        for (int j = 0; j < 4; ++j) {
            a0.h[j] = __hfma2(w0, u0.h[j], a0.h[j]);
            a1.h[j] = __hfma2(w1, u1.h[j], a1.h[j]);
            a2.h[j] = __hfma2(w2, u2.h[j], a2.h[j]);
            a3.h[j] = __hfma2(w3, u3.h[j], a3.h[j]);
        }
    }
    for (; k < end; ++k) {
        v2i e = __builtin_nontemporal_load((const v2i*)bins + k);
        U4H u; u.u = nfu4[(size_t)e.x * 16 + lane];
        __half2 w = __float2half2_rn(__int_as_float(e.y));
        #pragma unroll
        for (int j = 0; j < 4; ++j) a0.h[j] = __hfma2(w, u.h[j], a0.h[j]);
    }
    U4H s, sf;
    sf.u = nfu4[(size_t)v * 16 + lane];
    #pragma unroll
    for (int j = 0; j < 4; ++j) {
        __half2 t2 = __hadd2(__hadd2(a0.h[j], a1.h[j]), __hadd2(a2.h[j], a3.h[j]));
        s.h[j] = __hmul2(t2, sf.h[j]);
    }
    __builtin_nontemporal_store(*(v4u*)&s.u, (v4u*)x16 + (size_t)v * 16 + lane);
}

// ---- MFMA gemm: out = leaky_relu(x16 @ W16^T); B from global (L1-hot, R10-proven) ----
__global__ __launch_bounds__(256) void gemm16(const __half* __restrict__ x16,
                                              const __half* __restrict__ W16,
                                              float* __restrict__ out) {
    __shared__ _Float16 Xl[64 * 128];    // 16 KB
    int tid = threadIdx.x;

    int rbase = blockIdx.x * 64;
    for (int i = tid; i < 1024; i += 256) {
        int r = i >> 4, c = i & 15;
        int grow = rbase + r;
        v4u u = (v4u){0u, 0u, 0u, 0u};
        if (grow < NNODES)
            u = __builtin_nontemporal_load((const v4u*)x16 + (size_t)grow * 16 + c);
        *(v4u*)&Xl[r * 128 + ((c ^ (r & 7)) << 3)] = u;
    }
    __syncthreads();

    int wave = tid >> 6;
    int lane = tid & 63;
    int n = lane & 15;
    int g = lane >> 4;
    const v8h* w8 = (const v8h*)W16;   // row = 16 v8h chunks

    v4f acc[8];
    #pragma unroll
    for (int jb = 0; jb < 8; ++jb) acc[jb] = (v4f){0.f, 0.f, 0.f, 0.f};

    #pragma unroll
    for (int kb = 0; kb < 4; ++kb) {
        v8h a = *(v8h*)&Xl[(wave * 16 + n) * 128 + (((kb * 4 + g) ^ (n & 7)) << 3)];
        #pragma unroll
        for (int jb = 0; jb < 8; ++jb) {
            v8h b = w8[(jb * 16 + n) * 16 + kb * 4 + g];
            acc[jb] = __builtin_amdgcn_mfma_f32_16x16x32_f16(a, b, acc[jb], 0, 0, 0);
        }
    }

    int row0 = rbase + wave * 16 + g * 4;
    #pragma unroll
    for (int jb = 0; jb < 8; ++jb) {
        #pragma unroll
        for (int reg = 0; reg < 4; ++reg) {
            int r = row0 + reg;
            if (r < NNODES) {
                float v = acc[jb][reg];
                v = v >= 0.f ? v : NEG_SLOPE * v;
                __builtin_nontemporal_store(v, out + (size_t)r * 128 + jb * 16 + n);
            }
        }
    }
}

// ---- mid path (no pairs space): direct hist + 8-part fill ----
__global__ __launch_bounds__(256) void hist_dst4(const int* __restrict__ edst,
                                                 int* __restrict__ counts) {
    int i = blockIdx.x * 256 + threadIdx.x;
    if (i < NEDGES / 4) {
        int4 d = ((const int4*)edst)[i];
        atomicAdd(&counts[d.x], 1);
        atomicAdd(&counts[d.y], 1);
        atomicAdd(&counts[d.z], 1);
        atomicAdd(&counts[d.w], 1);
    }
}

__global__ __launch_bounds__(256) void fill_part(const int* __restrict__ esrc,
                                                 const int* __restrict__ edst,
                                                 const float* __restrict__ ew,
                                                 int* __restrict__ offsets,
                                                 int2* __restrict__ bins) {
    int part = blockIdx.x & (NPART - 1);
    int lo = part * PART_SZ;
    int hi = lo + PART_SZ;
    int t = (blockIdx.x >> 3) * 256 + threadIdx.x;
    int stride = (gridDim.x >> 3) * 256;
    int nq = NEDGES / 4;
    for (int i = t; i < nq; i += stride) {
        int4 d = ((const int4*)edst)[i];
        int e = i * 4;
        if (d.x >= lo && d.x < hi) {
            int p = atomicAdd(&offsets[d.x], 1);
            bins[p] = make_int2(esrc[e + 0], __float_as_int(ew[e + 0]));
        }
        if (d.y >= lo && d.y < hi) {
            int p = atomicAdd(&offsets[d.y], 1);
            bins[p] = make_int2(esrc[e + 1], __float_as_int(ew[e + 1]));
        }
        if (d.z >= lo && d.z < hi) {
            int p = atomicAdd(&offsets[d.z], 1);
            bins[p] = make_int2(esrc[e + 2], __float_as_int(ew[e + 2]));
        }
        if (d.w >= lo && d.w < hi) {
            int p = atomicAdd(&offsets[d.w], 1);
            bins[p] = make_int2(esrc[e + 3], __float_as_int(ew[e + 3]));
        }
    }
}

// ---- pull variant for mid path: bins hold plain (src, w) with full src ----
__global__ __launch_bounds__(256) void pull_x16_mid(const __half* __restrict__ nf16,
                                                    const int* __restrict__ offsets,
                                                    const int* __restrict__ counts,
                                                    const int2* __restrict__ bins,
                                                    __half* __restrict__ x16) {
    int gid = blockIdx.x * 256 + threadIdx.x;
    int v = gid >> 4;
    int lane = gid & 15;
    if (v >= NNODES) return;
    int end = offsets[v];
    int start = end - counts[v];
    const uint4* nfu4 = (const uint4*)nf16;
    __half2 z2 = __float2half2_rn(0.f);
    U4H a0;
    #pragma unroll
    for (int j = 0; j < 4; ++j) a0.h[j] = z2;
    for (int k = start; k < end; ++k) {
        v2i e = __builtin_nontemporal_load((const v2i*)bins + k);
        U4H u; u.u = nfu4[(size_t)e.x * 16 + lane];
        __half2 w = __float2half2_rn(__int_as_float(e.y));
        #pragma unroll
        for (int j = 0; j < 4; ++j) a0.h[j] = __hfma2(w, u.h[j], a0.h[j]);
    }
    U4H s, sf;
    sf.u = nfu4[(size_t)v * 16 + lane];
    #pragma unroll
    for (int j = 0; j < 4; ++j) s.h[j] = __hmul2(a0.h[j], sf.h[j]);
    __builtin_nontemporal_store(*(v4u*)&s.u, (v4u*)x16 + (size_t)v * 16 + lane);
}

// ---- last-resort fallback (f32, atomic scatter) ----
__global__ __launch_bounds__(256) void scatter_edges(
    const float* __restrict__ nfeat, const int* __restrict__ esrc,
    const int* __restrict__ edst, const float* __restrict__ ew,
    float* __restrict__ hn) {
    long long t = (long long)blockIdx.x * 256 + threadIdx.x;
    int e = (int)(t >> 5);
    if (e >= NEDGES) return;
    int lane = (int)(t & 31);
    int s = esrc[e];
    int d = edst[e];
    float w = ew[e];
    float4 v = ((const float4*)(nfeat + (size_t)s * DIM))[lane];
    float* o = hn + (size_t)d * DIM + lane * 4;
    unsafeAtomicAdd(o + 0, v.x * w);
    unsafeAtomicAdd(o + 1, v.y * w);
    unsafeAtomicAdd(o + 2, v.z * w);
    unsafeAtomicAdd(o + 3, v.w * w);
}

__global__ __launch_bounds__(256) void elem_mul(const float* __restrict__ nfeat,
                                                float* __restrict__ hn, int n4) {
    int i = blockIdx.x * blockDim.x + threadIdx.x;
    int stride = gridDim.x * blockDim.x;
    for (; i < n4; i += stride) {
        float4 a = ((const float4*)nfeat)[i];
        float4 b = ((float4*)hn)[i];
        b.x *= a.x; b.y *= a.y; b.z *= a.z; b.w *= a.w;
        ((float4*)hn)[i] = b;
    }
}

__global__ __launch_bounds__(256) void bi_gemm2(
    const float* __restrict__ x, const float* __restrict__ W,
    float* __restrict__ out) {
    extern __shared__ float lds[];
    float4* W4  = (float4*)lds;
    float*  xs  = lds + 128 * 128;
    float4* xs4 = (float4*)xs;
    int tid = threadIdx.x;
    const float4* Wg = (const float4*)W;
    for (int i = tid; i < 128 * 32; i += 256) {
        int j = i >> 5, d4 = i & 31;
        W4[(j << 5) | (d4 ^ ((j >> 2) & 7))] = Wg[i];
    }
    __syncthreads();
    int tx = tid & 31, ty = tid >> 5;
    int j0 = tx << 2, r0 = ty << 2;
    int ntiles = NNODES / 32;
    for (int tile = blockIdx.x; tile < ntiles; tile += gridDim.x) {
        int rbase = tile * 32;
        for (int i = tid; i < 32 * 32; i += 256)
            xs4[i] = ((const float4*)x)[(size_t)rbase * 32 + i];
        __syncthreads();
        float acc[4][4];
        #pragma unroll
        for (int r = 0; r < 4; ++r)
            #pragma unroll
            for (int j = 0; j < 4; ++j) acc[r][j] = 0.f;
        #pragma unroll 4
        for (int d4 = 0; d4 < 32; ++d4) {
            float4 xv[4], wv[4];
            #pragma unroll
            for (int r = 0; r < 4; ++r) xv[r] = xs4[((r0 + r) << 5) | d4];
            #pragma unroll
            for (int j = 0; j < 4; ++j) {
                int jj = j0 + j;
                wv[j] = W4[(jj << 5) | (d4 ^ ((jj >> 2) & 7))];
            }
            #pragma unroll
            for (int r = 0; r < 4; ++r)
                #pragma unroll
                for (int j = 0; j < 4; ++j) {
                    acc[r][j] += xv[r].x * wv[j].x;
                    acc[r][j] += xv[r].y * wv[j].y;
                    acc[r][j] += xv[r].z * wv[j].z;
                    acc[r][j] += xv[r].w * wv[j].w;
                }
        }
        __syncthreads();
        #pragma unroll
        for (int r = 0; r < 4; ++r) {
            float4 o;
            o.x = acc[r][0] >= 0.f ? acc[r][0] : NEG_SLOPE * acc[r][0];
            o.y = acc[r][1] >= 0.f ? acc[r][1] : NEG_SLOPE * acc[r][1];
            o.z = acc[r][2] >= 0.f ? acc[r][2] : NEG_SLOPE * acc[r][2];
            o.w = acc[r][3] >= 0.f ? acc[r][3] : NEG_SLOPE * acc[r][3];
            size_t row = (size_t)(rbase + r0 + r);
            ((float4*)out)[row * (DIM / 4) + tx] = o;
        }
    }
}

extern "C" void kernel_launch(void* const* d_in, const int* in_sizes, int n_in,
                              void* d_out, int out_size, void* d_ws, size_t ws_size,
                              hipStream_t stream) {
    const float* nfeat = (const float*)d_in[0];
    const int*   esrc  = (const int*)d_in[1];
    const int*   edst  = (const int*)d_in[2];
    const float* ew    = (const float*)d_in[3];
    const float* W     = (const float*)d_in[4];
    float* out = (float*)d_out;

    // ---- workspace layout ----
    size_t off = 0;
    size_t nf16_off = off;     off += align256((size_t)NNODES * DIM * 2);  // 25.6 MB
    size_t x16_off = off;      off += align256((size_t)NNODES * DIM * 2);  // 25.6 MB
    size_t w16_off = off;      off += align256((size_t)DIM * DIM * 2);     // 32 KB
    size_t cnt_off = off;      off += align256((size_t)NNODES * 4);
    size_t ofs_off = off;      off += align256((size_t)NNODES * 4);
    size_t scur_off = off;     off += align256((size_t)NSUB * SCUR_STRIDE * 4);
    size_t bsum_off = off;     off += align256((size_t)NB_SCAN * 4);
    size_t bins_off = off;     off += align256((size_t)NEDGES * 8);        // 12.8 MB
    size_t need_mid = off;
    size_t pair_off = off;     off += align256((size_t)NSUB * SCAP * 8);   // 13.8 MB
    size_t need_full = off;

    char* ws = (char*)d_ws;

    if (ws_size >= need_mid) {
        __half* nf16 = (__half*)(ws + nf16_off);
        __half* x16  = (__half*)(ws + x16_off);
        __half* W16  = (__half*)(ws + w16_off);
        int* counts = (int*)(ws + cnt_off);
        int* offsets = (int*)(ws + ofs_off);
        int* scur = (int*)(ws + scur_off);
        int* blocksum = (int*)(ws + bsum_off);
        int2* bins = (int2*)(ws + bins_off);
        int2* pairs = (int2*)(ws + pair_off);

        prep<<<2048, 256, 0, stream>>>(nfeat, W, nf16, W16, counts, scur);
        int pgrid = (NNODES * 16 + 255) / 256;   // 6250
        if (ws_size >= need_full) {
            int sgrid = (NEDGES + CHUNK - 1) / CHUNK;   // 782
            split_edges<<<sgrid, 256, 0, stream>>>(esrc, edst, ew, scur, pairs);
            hist_part<<<2048, 256, 0, stream>>>(pairs, scur, counts);
            scan1<<<NB_SCAN, 256, 0, stream>>>(counts, offsets, blocksum);
            scan2p<<<1, 128, 0, stream>>>(blocksum, NB_SCAN);
            scan3<<<NB_SCAN, 256, 0, stream>>>(offsets, blocksum);
            fill_part2<<<2048, 256, 0, stream>>>(pairs, scur, offsets, bins);
            pull_x16<<<pgrid, 256, 0, stream>>>(nf16, offsets, counts, bins, x16);
        } else {
            int e4grid = (NEDGES / 4 + 255) / 256;
            hist_dst4<<<e4grid, 256, 0, stream>>>(edst, counts);
            scan1<<<NB_SCAN, 256, 0, stream>>>(counts, offsets, blocksum);
            scan2p<<<1, 128, 0, stream>>>(blocksum, NB_SCAN);
            scan3<<<NB_SCAN, 256, 0, stream>>>(offsets, blocksum);
            fill_part<<<2048, 256, 0, stream>>>(esrc, edst, ew, offsets, bins);
            pull_x16_mid<<<pgrid, 256, 0, stream>>>(nf16, offsets, counts, bins, x16);
        }
        gemm16<<<GEMM_TILES, 256, 0, stream>>>(x16, W16, out);
    } else {
        // last resort: f32 atomic scatter + elementwise + VALU gemm
        float* hn = (float*)ws;
        hipFuncSetAttribute((const void*)bi_gemm2,
                            hipFuncAttributeMaxDynamicSharedMemorySize, 81920);
        zero_f32<<<2048, 256, 0, stream>>>(hn, NNODES * DIM / 4);
        int sgrid = (NEDGES * 32 + 255) / 256;
        scatter_edges<<<sgrid, 256, 0, stream>>>(nfeat, esrc, edst, ew, hn);
        elem_mul<<<2048, 256, 0, stream>>>(nfeat, hn, NNODES * DIM / 4);
        bi_gemm2<<<512, 256, 81920, stream>>>(hn, W, out);
    }
}

// Round 16
// 243.585 us; speedup vs baseline: 1.0711x; 1.0711x over previous
//
#include <hip/hip_runtime.h>
#include <hip/hip_fp16.h>

#define NNODES 100000
#define NEDGES 1600000
#define DIM    128
#define NEG_SLOPE 0.01f
#define NB_SCAN ((NNODES + 1023) / 1024)   // 98 blocks of 1024 counts
// mid-path (8-part) macros
#define NPART 8
#define PART_SZ ((NNODES + NPART - 1) / NPART)   // 12500
// full-path: 64 sub-parts; sp & 7 = XCD class (blocks for sp have b%8 == sp%8)
#define NSUB 64
#define SUB_SZ ((NNODES + NSUB - 1) / NSUB)      // 1563 (11 bits)
#define SCAP 27000                                // per-sub-part cap (exp 25000, ~13 sigma)
#define SCUR_STRIDE 32                            // pad counters to 128B
#define CHUNK 2048                                // edges per split block (8/thread)
#define GEMM_TILES ((NNODES + 63) / 64)           // 1563

typedef _Float16     v8h __attribute__((ext_vector_type(8)));
typedef float        v4f __attribute__((ext_vector_type(4)));
typedef int          v4i __attribute__((ext_vector_type(4)));
typedef int          v2i __attribute__((ext_vector_type(2)));
typedef float        v4x __attribute__((ext_vector_type(4)));
typedef unsigned int v2u __attribute__((ext_vector_type(2)));
typedef unsigned int v4u __attribute__((ext_vector_type(4)));

static inline size_t align256(size_t x) { return (x + 255) & ~(size_t)255; }

union HU { unsigned int u; __half2 h; };
union U4H { uint4 u; __half2 h[4]; };

// ---------------- zero (fallback) ----------------
__global__ __launch_bounds__(256) void zero_f32(float* __restrict__ p, int n4) {
    int i = blockIdx.x * blockDim.x + threadIdx.x;
    int stride = gridDim.x * blockDim.x;
    float4 z = make_float4(0.f, 0.f, 0.f, 0.f);
    for (; i < n4; i += stride) ((float4*)p)[i] = z;
}

// ---- prep: converts + zero counts/scur (R13-proven) ----
__global__ __launch_bounds__(256) void prep(const float* __restrict__ nf,
                                            const float* __restrict__ W,
                                            __half* __restrict__ nf16,
                                            __half* __restrict__ W16,
                                            int* __restrict__ counts,
                                            int* __restrict__ scur) {
    int i = blockIdx.x * 256 + threadIdx.x;
    int stride = gridDim.x * 256;
    for (int j = i; j < NNODES * DIM / 4; j += stride) {
        v4x v = __builtin_nontemporal_load((const v4x*)nf + j);
        HU a, b;
        a.h = __float22half2_rn(make_float2(v.x, v.y));
        b.h = __float22half2_rn(make_float2(v.z, v.w));
        ((uint2*)nf16)[j] = make_uint2(a.u, b.u);
    }
    const float4* Wg4 = (const float4*)W;
    for (int j = i; j < DIM * DIM / 8; j += stride) {
        float4 lo = Wg4[j * 2], hi = Wg4[j * 2 + 1];
        HU a, b, c, d;
        a.h = __float22half2_rn(make_float2(lo.x, lo.y));
        b.h = __float22half2_rn(make_float2(lo.z, lo.w));
        c.h = __float22half2_rn(make_float2(hi.x, hi.y));
        d.h = __float22half2_rn(make_float2(hi.z, hi.w));
        ((uint4*)W16)[j] = make_uint4(a.u, b.u, c.u, d.u);
    }
    v4i z = (v4i){0, 0, 0, 0};
    for (int j = i; j < NNODES / 4; j += stride)
        *((v4i*)counts + j) = z;
    if (i < NSUB * SCUR_STRIDE) scur[i] = 0;
}

// ---- pass A: 64-way split, 8 edges/thread, per-wave LDS-atomic rank (R13) ----
__global__ __launch_bounds__(256) void split_edges(const int* __restrict__ esrc,
                                                   const int* __restrict__ edst,
                                                   const float* __restrict__ ew,
                                                   int* __restrict__ scur,
                                                   int2* __restrict__ pairs) {
    __shared__ int wcnt[4][NSUB];
    __shared__ int wbase[4][NSUB];
    __shared__ int gbase[NSUB];
    int tid = threadIdx.x;
    int wave = tid >> 6;
    ((int*)wcnt)[tid] = 0;            // 4*64 == 256
    __syncthreads();

    int nq = NEDGES / 4;
    int qA = blockIdx.x * (CHUNK / 4) + tid;
    int qB = qA + 256;

    v4i dA = (v4i){0,0,0,0}, sA = (v4i){0,0,0,0};
    v4x wA = (v4x){0,0,0,0};
    v4i dB = (v4i){0,0,0,0}, sB = (v4i){0,0,0,0};
    v4x wB = (v4x){0,0,0,0};
    bool vA = qA < nq, vB = qB < nq;
    if (vA) {
        dA = __builtin_nontemporal_load((const v4i*)edst + qA);
        sA = __builtin_nontemporal_load((const v4i*)esrc + qA);
        wA = __builtin_nontemporal_load((const v4x*)ew + qA);
    }
    if (vB) {
        dB = __builtin_nontemporal_load((const v4i*)edst + qB);
        sB = __builtin_nontemporal_load((const v4i*)esrc + qB);
        wB = __builtin_nontemporal_load((const v4x*)ew + qB);
    }

    int sp8[8]; int rnk[8]; int2 pv[8];
    #pragma unroll
    for (int k = 0; k < 4; ++k) {
        int d = dA[k], s = sA[k];
        int p = vA ? (int)((unsigned)d / SUB_SZ) : -1;
        sp8[k] = p;
        pv[k] = make_int2(((d - p * SUB_SZ) << 17) | s, __float_as_int(wA[k]));
        int d2 = dB[k], s2 = sB[k];
        int p2 = vB ? (int)((unsigned)d2 / SUB_SZ) : -1;
        sp8[k + 4] = p2;
        pv[k + 4] = make_int2(((d2 - p2 * SUB_SZ) << 17) | s2, __float_as_int(wB[k]));
    }

    #pragma unroll
    for (int s = 0; s < 8; ++s) {
        if (sp8[s] >= 0)
            rnk[s] = atomicAdd(&wcnt[wave][sp8[s]], 1);   // avg 1 lane/bucket
    }
    __syncthreads();
    if (tid < NSUB) {
        int t0 = wcnt[0][tid], t1 = wcnt[1][tid], t2 = wcnt[2][tid], t3 = wcnt[3][tid];
        wbase[0][tid] = 0; wbase[1][tid] = t0;
        wbase[2][tid] = t0 + t1; wbase[3][tid] = t0 + t1 + t2;
        gbase[tid] = atomicAdd(&scur[tid * SCUR_STRIDE], t0 + t1 + t2 + t3);
    }
    __syncthreads();

    #pragma unroll
    for (int s = 0; s < 8; ++s) {
        int p = sp8[s];
        if (p >= 0) {
            int slot = gbase[p] + wbase[wave][p] + rnk[s];
            if (slot < SCAP)
                pairs[(size_t)p * SCAP + slot] = pv[s];
        }
    }
}

// ---- pass B: per-sub-part histogram (6KB window), 4 records/iter (R13) ----
__global__ __launch_bounds__(256) void hist_part(const int2* __restrict__ pairs,
                                                 const int* __restrict__ scur,
                                                 int* __restrict__ counts) {
    int b = blockIdx.x;
    int sp = b & 63;
    int w = b >> 6;                               // 0..31
    int n = scur[sp * SCUR_STRIDE];
    if (n > SCAP) n = SCAP;
    const int2* base = pairs + (size_t)sp * SCAP;
    int cbase = sp * SUB_SZ;
    int ng = n >> 2;                              // groups of 4 records
    for (int i = w * 256 + threadIdx.x; i < ng; i += 8192) {
        v4i a = __builtin_nontemporal_load((const v4i*)base + 2 * i);
        v4i c = __builtin_nontemporal_load((const v4i*)base + 2 * i + 1);
        atomicAdd(&counts[cbase + ((unsigned)a.x >> 17)], 1);
        atomicAdd(&counts[cbase + ((unsigned)a.z >> 17)], 1);
        atomicAdd(&counts[cbase + ((unsigned)c.x >> 17)], 1);
        atomicAdd(&counts[cbase + ((unsigned)c.z >> 17)], 1);
    }
    if (w == 0 && threadIdx.x < 3) {
        int idx = (ng << 2) + threadIdx.x;
        if (idx < n) {
            int2 pr = base[idx];
            atomicAdd(&counts[cbase + ((unsigned)pr.x >> 17)], 1);
        }
    }
}

// ---- scan step 1 (R13) ----
__global__ __launch_bounds__(256) void scan1(const int* __restrict__ counts,
                                             int* __restrict__ offsets,
                                             int* __restrict__ blocksum) {
    __shared__ int lds[256];
    int tid = threadIdx.x;
    int base = blockIdx.x * 1024 + tid * 4;
    int c0 = (base + 0 < NNODES) ? counts[base + 0] : 0;
    int c1 = (base + 1 < NNODES) ? counts[base + 1] : 0;
    int c2 = (base + 2 < NNODES) ? counts[base + 2] : 0;
    int c3 = (base + 3 < NNODES) ? counts[base + 3] : 0;
    int t = c0 + c1 + c2 + c3;
    lds[tid] = t;
    __syncthreads();
    for (int d = 1; d < 256; d <<= 1) {
        int v = lds[tid];
        int add = (tid >= d) ? lds[tid - d] : 0;
        __syncthreads();
        lds[tid] = v + add;
        __syncthreads();
    }
    int incl = lds[tid];
    int excl = incl - t;
    if (base + 0 < NNODES) offsets[base + 0] = excl;
    if (base + 1 < NNODES) offsets[base + 1] = excl + c0;
    if (base + 2 < NNODES) offsets[base + 2] = excl + c0 + c1;
    if (base + 3 < NNODES) offsets[base + 3] = excl + c0 + c1 + c2;
    if (tid == 255) blocksum[blockIdx.x] = incl;
}

// ---- scan step 2 (R13) ----
__global__ __launch_bounds__(128) void scan2p(int* __restrict__ blocksum, int nb) {
    __shared__ int lds[128];
    int tid = threadIdx.x;
    int v = (tid < nb) ? blocksum[tid] : 0;
    lds[tid] = v;
    __syncthreads();
    for (int d = 1; d < 128; d <<= 1) {
        int x = lds[tid];
        int add = (tid >= d) ? lds[tid - d] : 0;
        __syncthreads();
        lds[tid] = x + add;
        __syncthreads();
    }
    if (tid < nb) blocksum[tid] = lds[tid] - v;   // exclusive
}

// ---- scan step 3: finalize offsets (doubles as fill cursor) (R13) ----
__global__ __launch_bounds__(256) void scan3(int* __restrict__ offsets,
                                             const int* __restrict__ blocksum) {
    int add = blocksum[blockIdx.x];
    int base = blockIdx.x * 1024 + threadIdx.x * 4;
    #pragma unroll
    for (int i = 0; i < 4; ++i) {
        int idx = base + i;
        if (idx < NNODES) offsets[idx] += add;
    }
}

// ---- pass C: fill bins per sub-part (~200KB dirty window, L2-resident) (R13) ----
__global__ __launch_bounds__(256) void fill_part2(const int2* __restrict__ pairs,
                                                  const int* __restrict__ scur,
                                                  int* __restrict__ offsets,
                                                  int2* __restrict__ bins) {
    int b = blockIdx.x;
    int sp = b & 63;
    int w = b >> 6;
    int n = scur[sp * SCUR_STRIDE];
    if (n > SCAP) n = SCAP;
    const int2* base = pairs + (size_t)sp * SCAP;
    int cbase = sp * SUB_SZ;
    int ng = n >> 2;
    for (int i = w * 256 + threadIdx.x; i < ng; i += 8192) {
        v4i a = __builtin_nontemporal_load((const v4i*)base + 2 * i);
        v4i c = __builtin_nontemporal_load((const v4i*)base + 2 * i + 1);
        int d0 = cbase + ((unsigned)a.x >> 17);
        int p0 = atomicAdd(&offsets[d0], 1);
        bins[p0] = make_int2(a.x & 0x1FFFF, a.y);
        int d1 = cbase + ((unsigned)a.z >> 17);
        int p1 = atomicAdd(&offsets[d1], 1);
        bins[p1] = make_int2(a.z & 0x1FFFF, a.w);
        int d2 = cbase + ((unsigned)c.x >> 17);
        int p2 = atomicAdd(&offsets[d2], 1);
        bins[p2] = make_int2(c.x & 0x1FFFF, c.y);
        int d3 = cbase + ((unsigned)c.z >> 17);
        int p3 = atomicAdd(&offsets[d3], 1);
        bins[p3] = make_int2(c.z & 0x1FFFF, c.w);
    }
    if (w == 0 && threadIdx.x < 3) {
        int idx = (ng << 2) + threadIdx.x;
        if (idx < n) {
            int2 pr = base[idx];
            int d = cbase + ((unsigned)pr.x >> 17);
            int p = atomicAdd(&offsets[d], 1);
            bins[p] = make_int2(pr.x & 0x1FFFF, pr.y);
        }
    }
}

// ---- pull: 16 lanes/node, uint4 gathers, packed-f16 accumulate (R15-proven) ----
// offsets holds END pointer after fill; start = end - counts[v].
__global__ __launch_bounds__(256) void pull_x16(const __half* __restrict__ nf16,
                                                const int* __restrict__ offsets,
                                                const int* __restrict__ counts,
                                                const int2* __restrict__ bins,
                                                __half* __restrict__ x16) {
    int gid = blockIdx.x * 256 + threadIdx.x;
    int v = gid >> 4;
    int lane = gid & 15;
    if (v >= NNODES) return;
    int end = offsets[v];
    int start = end - counts[v];
    const uint4* nfu4 = (const uint4*)nf16;   // row = 16 uint4
    __half2 z2 = __float2half2_rn(0.f);
    U4H a0, a1, a2, a3;
    #pragma unroll
    for (int j = 0; j < 4; ++j) { a0.h[j] = z2; a1.h[j] = z2; a2.h[j] = z2; a3.h[j] = z2; }
    int k = start;
    for (; k + 4 <= end; k += 4) {
        v2i e0 = __builtin_nontemporal_load((const v2i*)bins + k);
        v2i e1 = __builtin_nontemporal_load((const v2i*)bins + k + 1);
        v2i e2 = __builtin_nontemporal_load((const v2i*)bins + k + 2);
        v2i e3 = __builtin_nontemporal_load((const v2i*)bins + k + 3);
        U4H u0, u1, u2, u3;
        u0.u = nfu4[(size_t)e0.x * 16 + lane];
        u1.u = nfu4[(size_t)e1.x * 16 + lane];
        u2.u = nfu4[(size_t)e2.x * 16 + lane];
        u3.u = nfu4[(size_t)e3.x * 16 + lane];
        __half2 w0 = __float2half2_rn(__int_as_float(e0.y));
        __half2 w1 = __float2half2_rn(__int_as_float(e1.y));
        __half2 w2 = __float2half2_rn(__int_as_float(e2.y));
        __half2 w3 = __float2half2_rn(__int_as_float(e3.y));
        #pragma unroll
        for (int j = 0; j < 4; ++j) {
            a0.h[j] = __hfma2(w0, u0.h[j], a0.h[j]);
            a1.h[j] = __hfma2(w1, u1.h[j], a1.h[j]);
            a2.h[j] = __hfma2(w2, u2.h[j], a2.h[j]);
            a3.h[j] = __hfma2(w3, u3.h[j], a3.h[j]);
        }
    }
    for (; k < end; ++k) {
        v2i e = __builtin_nontemporal_load((const v2i*)bins + k);
        U4H u; u.u = nfu4[(size_t)e.x * 16 + lane];
        __half2 w = __float2half2_rn(__int_as_float(e.y));
        #pragma unroll
        for (int j = 0; j < 4; ++j) a0.h[j] = __hfma2(w, u.h[j], a0.h[j]);
    }
    U4H s, sf;
    sf.u = nfu4[(size_t)v * 16 + lane];
    #pragma unroll
    for (int j = 0; j < 4; ++j) {
        __half2 t2 = __hadd2(__hadd2(a0.h[j], a1.h[j]), __hadd2(a2.h[j], a3.h[j]));
        s.h[j] = __hmul2(t2, sf.h[j]);
    }
    __builtin_nontemporal_store(*(v4u*)&s.u, (v4u*)x16 + (size_t)v * 16 + lane);
}

// ---- MFMA gemm: out = leaky_relu(x16 @ W16^T), W16 staged in LDS (R13-proven) ----
__global__ __launch_bounds__(256) void gemm16(const __half* __restrict__ x16,
                                              const __half* __restrict__ W16,
                                              float* __restrict__ out) {
    __shared__ _Float16 Wl[128 * 128];   // 32 KB
    __shared__ _Float16 Xl[64 * 128];    // 16 KB
    int tid = threadIdx.x;

    const v4u* Wg = (const v4u*)W16;
    for (int i = tid; i < 2048; i += 256) {
        int r = i >> 4, c = i & 15;
        v4u u = Wg[i];
        *(v4u*)&Wl[r * 128 + ((c ^ (r & 7)) << 3)] = u;
    }

    int rbase = blockIdx.x * 64;
    for (int i = tid; i < 1024; i += 256) {
        int r = i >> 4, c = i & 15;
        int grow = rbase + r;
        v4u u = (v4u){0u, 0u, 0u, 0u};
        if (grow < NNODES)
            u = __builtin_nontemporal_load((const v4u*)x16 + (size_t)grow * 16 + c);
        *(v4u*)&Xl[r * 128 + ((c ^ (r & 7)) << 3)] = u;
    }
    __syncthreads();

    int wave = tid >> 6;
    int lane = tid & 63;
    int n = lane & 15;
    int g = lane >> 4;

    v4f acc[8];
    #pragma unroll
    for (int jb = 0; jb < 8; ++jb) acc[jb] = (v4f){0.f, 0.f, 0.f, 0.f};

    #pragma unroll
    for (int kb = 0; kb < 4; ++kb) {
        v8h a = *(v8h*)&Xl[(wave * 16 + n) * 128 + (((kb * 4 + g) ^ (n & 7)) << 3)];
        #pragma unroll
        for (int jb = 0; jb < 8; ++jb) {
            v8h b = *(v8h*)&Wl[(jb * 16 + n) * 128 + (((kb * 4 + g) ^ (n & 7)) << 3)];
            acc[jb] = __builtin_amdgcn_mfma_f32_16x16x32_f16(a, b, acc[jb], 0, 0, 0);
        }
    }

    int row0 = rbase + wave * 16 + g * 4;
    #pragma unroll
    for (int jb = 0; jb < 8; ++jb) {
        #pragma unroll
        for (int reg = 0; reg < 4; ++reg) {
            int r = row0 + reg;
            if (r < NNODES) {
                float v = acc[jb][reg];
                v = v >= 0.f ? v : NEG_SLOPE * v;
                __builtin_nontemporal_store(v, out + (size_t)r * 128 + jb * 16 + n);
            }
        }
    }
}

// ---- mid path (no pairs space): direct hist + 8-part fill ----
__global__ __launch_bounds__(256) void hist_dst4(const int* __restrict__ edst,
                                                 int* __restrict__ counts) {
    int i = blockIdx.x * 256 + threadIdx.x;
    if (i < NEDGES / 4) {
        int4 d = ((const int4*)edst)[i];
        atomicAdd(&counts[d.x], 1);
        atomicAdd(&counts[d.y], 1);
        atomicAdd(&counts[d.z], 1);
        atomicAdd(&counts[d.w], 1);
    }
}

__global__ __launch_bounds__(256) void fill_part(const int* __restrict__ esrc,
                                                 const int* __restrict__ edst,
                                                 const float* __restrict__ ew,
                                                 int* __restrict__ offsets,
                                                 int2* __restrict__ bins) {
    int part = blockIdx.x & (NPART - 1);
    int lo = part * PART_SZ;
    int hi = lo + PART_SZ;
    int t = (blockIdx.x >> 3) * 256 + threadIdx.x;
    int stride = (gridDim.x >> 3) * 256;
    int nq = NEDGES / 4;
    for (int i = t; i < nq; i += stride) {
        int4 d = ((const int4*)edst)[i];
        int e = i * 4;
        if (d.x >= lo && d.x < hi) {
            int p = atomicAdd(&offsets[d.x], 1);
            bins[p] = make_int2(esrc[e + 0], __float_as_int(ew[e + 0]));
        }
        if (d.y >= lo && d.y < hi) {
            int p = atomicAdd(&offsets[d.y], 1);
            bins[p] = make_int2(esrc[e + 1], __float_as_int(ew[e + 1]));
        }
        if (d.z >= lo && d.z < hi) {
            int p = atomicAdd(&offsets[d.z], 1);
            bins[p] = make_int2(esrc[e + 2], __float_as_int(ew[e + 2]));
        }
        if (d.w >= lo && d.w < hi) {
            int p = atomicAdd(&offsets[d.w], 1);
            bins[p] = make_int2(esrc[e + 3], __float_as_int(ew[e + 3]));
        }
    }
}

// ---- pull variant for mid path: bins hold plain (src, w) ----
__global__ __launch_bounds__(256) void pull_x16_mid(const __half* __restrict__ nf16,
                                                    const int* __restrict__ offsets,
                                                    const int* __restrict__ counts,
                                                    const int2* __restrict__ bins,
                                                    __half* __restrict__ x16) {
    int gid = blockIdx.x * 256 + threadIdx.x;
    int v = gid >> 4;
    int lane = gid & 15;
    if (v >= NNODES) return;
    int end = offsets[v];
    int start = end - counts[v];
    const uint4* nfu4 = (const uint4*)nf16;
    __half2 z2 = __float2half2_rn(0.f);
    U4H a0;
    #pragma unroll
    for (int j = 0; j < 4; ++j) a0.h[j] = z2;
    for (int k = start; k < end; ++k) {
        v2i e = __builtin_nontemporal_load((const v2i*)bins + k);
        U4H u; u.u = nfu4[(size_t)e.x * 16 + lane];
        __half2 w = __float2half2_rn(__int_as_float(e.y));
        #pragma unroll
        for (int j = 0; j < 4; ++j) a0.h[j] = __hfma2(w, u.h[j], a0.h[j]);
    }
    U4H s, sf;
    sf.u = nfu4[(size_t)v * 16 + lane];
    #pragma unroll
    for (int j = 0; j < 4; ++j) s.h[j] = __hmul2(a0.h[j], sf.h[j]);
    __builtin_nontemporal_store(*(v4u*)&s.u, (v4u*)x16 + (size_t)v * 16 + lane);
}

// ---- last-resort fallback (f32, atomic scatter) ----
__global__ __launch_bounds__(256) void scatter_edges(
    const float* __restrict__ nfeat, const int* __restrict__ esrc,
    const int* __restrict__ edst, const float* __restrict__ ew,
    float* __restrict__ hn) {
    long long t = (long long)blockIdx.x * 256 + threadIdx.x;
    int e = (int)(t >> 5);
    if (e >= NEDGES) return;
    int lane = (int)(t & 31);
    int s = esrc[e];
    int d = edst[e];
    float w = ew[e];
    float4 v = ((const float4*)(nfeat + (size_t)s * DIM))[lane];
    float* o = hn + (size_t)d * DIM + lane * 4;
    unsafeAtomicAdd(o + 0, v.x * w);
    unsafeAtomicAdd(o + 1, v.y * w);
    unsafeAtomicAdd(o + 2, v.z * w);
    unsafeAtomicAdd(o + 3, v.w * w);
}

__global__ __launch_bounds__(256) void elem_mul(const float* __restrict__ nfeat,
                                                float* __restrict__ hn, int n4) {
    int i = blockIdx.x * blockDim.x + threadIdx.x;
    int stride = gridDim.x * blockDim.x;
    for (; i < n4; i += stride) {
        float4 a = ((const float4*)nfeat)[i];
        float4 b = ((float4*)hn)[i];
        b.x *= a.x; b.y *= a.y; b.z *= a.z; b.w *= a.w;
        ((float4*)hn)[i] = b;
    }
}

__global__ __launch_bounds__(256) void bi_gemm2(
    const float* __restrict__ x, const float* __restrict__ W,
    float* __restrict__ out) {
    extern __shared__ float lds[];
    float4* W4  = (float4*)lds;
    float*  xs  = lds + 128 * 128;
    float4* xs4 = (float4*)xs;
    int tid = threadIdx.x;
    const float4* Wg = (const float4*)W;
    for (int i = tid; i < 128 * 32; i += 256) {
        int j = i >> 5, d4 = i & 31;
        W4[(j << 5) | (d4 ^ ((j >> 2) & 7))] = Wg[i];
    }
    __syncthreads();
    int tx = tid & 31, ty = tid >> 5;
    int j0 = tx << 2, r0 = ty << 2;
    int ntiles = NNODES / 32;
    for (int tile = blockIdx.x; tile < ntiles; tile += gridDim.x) {
        int rbase = tile * 32;
        for (int i = tid; i < 32 * 32; i += 256)
            xs4[i] = ((const float4*)x)[(size_t)rbase * 32 + i];
        __syncthreads();
        float acc[4][4];
        #pragma unroll
        for (int r = 0; r < 4; ++r)
            #pragma unroll
            for (int j = 0; j < 4; ++j) acc[r][j] = 0.f;
        #pragma unroll 4
        for (int d4 = 0; d4 < 32; ++d4) {
            float4 xv[4], wv[4];
            #pragma unroll
            for (int r = 0; r < 4; ++r) xv[r] = xs4[((r0 + r) << 5) | d4];
            #pragma unroll
            for (int j = 0; j < 4; ++j) {
                int jj = j0 + j;
                wv[j] = W4[(jj << 5) | (d4 ^ ((jj >> 2) & 7))];
            }
            #pragma unroll
            for (int r = 0; r < 4; ++r)
                #pragma unroll
                for (int j = 0; j < 4; ++j) {
                    acc[r][j] += xv[r].x * wv[j].x;
                    acc[r][j] += xv[r].y * wv[j].y;
                    acc[r][j] += xv[r].z * wv[j].z;
                    acc[r][j] += xv[r].w * wv[j].w;
                }
        }
        __syncthreads();
        #pragma unroll
        for (int r = 0; r < 4; ++r) {
            float4 o;
            o.x = acc[r][0] >= 0.f ? acc[r][0] : NEG_SLOPE * acc[r][0];
            o.y = acc[r][1] >= 0.f ? acc[r][1] : NEG_SLOPE * acc[r][1];
            o.z = acc[r][2] >= 0.f ? acc[r][2] : NEG_SLOPE * acc[r][2];
            o.w = acc[r][3] >= 0.f ? acc[r][3] : NEG_SLOPE * acc[r][3];
            size_t row = (size_t)(rbase + r0 + r);
            ((float4*)out)[row * (DIM / 4) + tx] = o;
        }
    }
}

extern "C" void kernel_launch(void* const* d_in, const int* in_sizes, int n_in,
                              void* d_out, int out_size, void* d_ws, size_t ws_size,
                              hipStream_t stream) {
    const float* nfeat = (const float*)d_in[0];
    const int*   esrc  = (const int*)d_in[1];
    const int*   edst  = (const int*)d_in[2];
    const float* ew    = (const float*)d_in[3];
    const float* W     = (const float*)d_in[4];
    float* out = (float*)d_out;

    // ---- workspace layout ----
    size_t off = 0;
    size_t nf16_off = off;     off += align256((size_t)NNODES * DIM * 2);  // 25.6 MB
    size_t x16_off = off;      off += align256((size_t)NNODES * DIM * 2);  // 25.6 MB
    size_t w16_off = off;      off += align256((size_t)DIM * DIM * 2);     // 32 KB
    size_t cnt_off = off;      off += align256((size_t)NNODES * 4);
    size_t ofs_off = off;      off += align256((size_t)NNODES * 4);
    size_t scur_off = off;     off += align256((size_t)NSUB * SCUR_STRIDE * 4);
    size_t bsum_off = off;     off += align256((size_t)NB_SCAN * 4);
    size_t bins_off = off;     off += align256((size_t)NEDGES * 8);        // 12.8 MB
    size_t need_mid = off;
    size_t pair_off = off;     off += align256((size_t)NSUB * SCAP * 8);   // 13.8 MB
    size_t need_full = off;

    char* ws = (char*)d_ws;

    if (ws_size >= need_mid) {
        __half* nf16 = (__half*)(ws + nf16_off);
        __half* x16  = (__half*)(ws + x16_off);
        __half* W16  = (__half*)(ws + w16_off);
        int* counts = (int*)(ws + cnt_off);
        int* offsets = (int*)(ws + ofs_off);
        int* scur = (int*)(ws + scur_off);
        int* blocksum = (int*)(ws + bsum_off);
        int2* bins = (int2*)(ws + bins_off);
        int2* pairs = (int2*)(ws + pair_off);

        prep<<<2048, 256, 0, stream>>>(nfeat, W, nf16, W16, counts, scur);
        int pgrid = (NNODES * 16 + 255) / 256;   // 6250
        if (ws_size >= need_full) {
            int sgrid = (NEDGES + CHUNK - 1) / CHUNK;   // 782
            split_edges<<<sgrid, 256, 0, stream>>>(esrc, edst, ew, scur, pairs);
            hist_part<<<2048, 256, 0, stream>>>(pairs, scur, counts);
            scan1<<<NB_SCAN, 256, 0, stream>>>(counts, offsets, blocksum);
            scan2p<<<1, 128, 0, stream>>>(blocksum, NB_SCAN);
            scan3<<<NB_SCAN, 256, 0, stream>>>(offsets, blocksum);
            fill_part2<<<2048, 256, 0, stream>>>(pairs, scur, offsets, bins);
            pull_x16<<<pgrid, 256, 0, stream>>>(nf16, offsets, counts, bins, x16);
        } else {
            int e4grid = (NEDGES / 4 + 255) / 256;
            hist_dst4<<<e4grid, 256, 0, stream>>>(edst, counts);
            scan1<<<NB_SCAN, 256, 0, stream>>>(counts, offsets, blocksum);
            scan2p<<<1, 128, 0, stream>>>(blocksum, NB_SCAN);
            scan3<<<NB_SCAN, 256, 0, stream>>>(offsets, blocksum);
            fill_part<<<e4grid, 256, 0, stream>>>(esrc, edst, ew, offsets, bins);
            pull_x16_mid<<<pgrid, 256, 0, stream>>>(nf16, offsets, counts, bins, x16);
        }
        gemm16<<<GEMM_TILES, 256, 0, stream>>>(x16, W16, out);
    } else {
        // last resort: f32 atomic scatter + elementwise + VALU gemm
        float* hn = (float*)ws;
        hipFuncSetAttribute((const void*)bi_gemm2,
                            hipFuncAttributeMaxDynamicSharedMemorySize, 81920);
        zero_f32<<<2048, 256, 0, stream>>>(hn, NNODES * DIM / 4);
        int sgrid = (NEDGES * 32 + 255) / 256;
        scatter_edges<<<sgrid, 256, 0, stream>>>(nfeat, esrc, edst, ew, hn);
        elem_mul<<<2048, 256, 0, stream>>>(nfeat, hn, NNODES * DIM / 4);
        bi_gemm2<<<512, 256, 81920, stream>>>(hn, W, out);
    }
}

// Round 17
// 240.462 us; speedup vs baseline: 1.0850x; 1.0130x over previous
//
#include <hip/hip_runtime.h>
#include <hip/hip_fp16.h>

#define NNODES 100000
#define NEDGES 1600000
#define DIM    128
#define NEG_SLOPE 0.01f
#define NB_SCAN ((NNODES + 1023) / 1024)   // 98 blocks of 1024 counts
// mid-path (8-part) macros
#define NPART 8
#define PART_SZ ((NNODES + NPART - 1) / NPART)   // 12500
// full-path: 64 sub-parts; sp & 7 = XCD class (blocks for sp have b%8 == sp%8)
#define NSUB 64
#define SUB_SZ ((NNODES + NSUB - 1) / NSUB)      // 1563 (11 bits)
#define SCAP 27000                                // per-sub-part cap (exp 25000, ~13 sigma)
#define SCUR_STRIDE 32                            // pad counters to 128B
#define CHUNK 2048                                // edges per split block (8/thread)
#define GEMM_TILES ((NNODES + 63) / 64)           // 1563

typedef _Float16     v8h __attribute__((ext_vector_type(8)));
typedef float        v4f __attribute__((ext_vector_type(4)));
typedef int          v4i __attribute__((ext_vector_type(4)));
typedef int          v2i __attribute__((ext_vector_type(2)));
typedef float        v4x __attribute__((ext_vector_type(4)));
typedef unsigned int v2u __attribute__((ext_vector_type(2)));
typedef unsigned int v4u __attribute__((ext_vector_type(4)));

static inline size_t align256(size_t x) { return (x + 255) & ~(size_t)255; }

union HU { unsigned int u; __half2 h; };
union U4H { uint4 u; __half2 h[4]; };

// ---------------- zero (fallback) ----------------
__global__ __launch_bounds__(256) void zero_f32(float* __restrict__ p, int n4) {
    int i = blockIdx.x * blockDim.x + threadIdx.x;
    int stride = gridDim.x * blockDim.x;
    float4 z = make_float4(0.f, 0.f, 0.f, 0.f);
    for (; i < n4; i += stride) ((float4*)p)[i] = z;
}

// ---- prep: converts + zero counts/scur (R13-proven) ----
__global__ __launch_bounds__(256) void prep(const float* __restrict__ nf,
                                            const float* __restrict__ W,
                                            __half* __restrict__ nf16,
                                            __half* __restrict__ W16,
                                            int* __restrict__ counts,
                                            int* __restrict__ scur) {
    int i = blockIdx.x * 256 + threadIdx.x;
    int stride = gridDim.x * 256;
    for (int j = i; j < NNODES * DIM / 4; j += stride) {
        v4x v = __builtin_nontemporal_load((const v4x*)nf + j);
        HU a, b;
        a.h = __float22half2_rn(make_float2(v.x, v.y));
        b.h = __float22half2_rn(make_float2(v.z, v.w));
        ((uint2*)nf16)[j] = make_uint2(a.u, b.u);
    }
    const float4* Wg4 = (const float4*)W;
    for (int j = i; j < DIM * DIM / 8; j += stride) {
        float4 lo = Wg4[j * 2], hi = Wg4[j * 2 + 1];
        HU a, b, c, d;
        a.h = __float22half2_rn(make_float2(lo.x, lo.y));
        b.h = __float22half2_rn(make_float2(lo.z, lo.w));
        c.h = __float22half2_rn(make_float2(hi.x, hi.y));
        d.h = __float22half2_rn(make_float2(hi.z, hi.w));
        ((uint4*)W16)[j] = make_uint4(a.u, b.u, c.u, d.u);
    }
    v4i z = (v4i){0, 0, 0, 0};
    for (int j = i; j < NNODES / 4; j += stride)
        *((v4i*)counts + j) = z;
    if (i < NSUB * SCUR_STRIDE) scur[i] = 0;
}

// ---- pass A: 64-way split, 8 edges/thread, per-wave LDS-atomic rank (R13) ----
__global__ __launch_bounds__(256) void split_edges(const int* __restrict__ esrc,
                                                   const int* __restrict__ edst,
                                                   const float* __restrict__ ew,
                                                   int* __restrict__ scur,
                                                   int2* __restrict__ pairs) {
    __shared__ int wcnt[4][NSUB];
    __shared__ int wbase[4][NSUB];
    __shared__ int gbase[NSUB];
    int tid = threadIdx.x;
    int wave = tid >> 6;
    ((int*)wcnt)[tid] = 0;            // 4*64 == 256
    __syncthreads();

    int nq = NEDGES / 4;
    int qA = blockIdx.x * (CHUNK / 4) + tid;
    int qB = qA + 256;

    v4i dA = (v4i){0,0,0,0}, sA = (v4i){0,0,0,0};
    v4x wA = (v4x){0,0,0,0};
    v4i dB = (v4i){0,0,0,0}, sB = (v4i){0,0,0,0};
    v4x wB = (v4x){0,0,0,0};
    bool vA = qA < nq, vB = qB < nq;
    if (vA) {
        dA = __builtin_nontemporal_load((const v4i*)edst + qA);
        sA = __builtin_nontemporal_load((const v4i*)esrc + qA);
        wA = __builtin_nontemporal_load((const v4x*)ew + qA);
    }
    if (vB) {
        dB = __builtin_nontemporal_load((const v4i*)edst + qB);
        sB = __builtin_nontemporal_load((const v4i*)esrc + qB);
        wB = __builtin_nontemporal_load((const v4x*)ew + qB);
    }

    int sp8[8]; int rnk[8]; int2 pv[8];
    #pragma unroll
    for (int k = 0; k < 4; ++k) {
        int d = dA[k], s = sA[k];
        int p = vA ? (int)((unsigned)d / SUB_SZ) : -1;
        sp8[k] = p;
        pv[k] = make_int2(((d - p * SUB_SZ) << 17) | s, __float_as_int(wA[k]));
        int d2 = dB[k], s2 = sB[k];
        int p2 = vB ? (int)((unsigned)d2 / SUB_SZ) : -1;
        sp8[k + 4] = p2;
        pv[k + 4] = make_int2(((d2 - p2 * SUB_SZ) << 17) | s2, __float_as_int(wB[k]));
    }

    #pragma unroll
    for (int s = 0; s < 8; ++s) {
        if (sp8[s] >= 0)
            rnk[s] = atomicAdd(&wcnt[wave][sp8[s]], 1);   // avg 1 lane/bucket
    }
    __syncthreads();
    if (tid < NSUB) {
        int t0 = wcnt[0][tid], t1 = wcnt[1][tid], t2 = wcnt[2][tid], t3 = wcnt[3][tid];
        wbase[0][tid] = 0; wbase[1][tid] = t0;
        wbase[2][tid] = t0 + t1; wbase[3][tid] = t0 + t1 + t2;
        gbase[tid] = atomicAdd(&scur[tid * SCUR_STRIDE], t0 + t1 + t2 + t3);
    }
    __syncthreads();

    #pragma unroll
    for (int s = 0; s < 8; ++s) {
        int p = sp8[s];
        if (p >= 0) {
            int slot = gbase[p] + wbase[wave][p] + rnk[s];
            if (slot < SCAP)
                pairs[(size_t)p * SCAP + slot] = pv[s];
        }
    }
}

// ---- pass B: per-sub-part histogram (6KB window), 4 records/iter (R13) ----
__global__ __launch_bounds__(256) void hist_part(const int2* __restrict__ pairs,
                                                 const int* __restrict__ scur,
                                                 int* __restrict__ counts) {
    int b = blockIdx.x;
    int sp = b & 63;
    int w = b >> 6;                               // 0..31
    int n = scur[sp * SCUR_STRIDE];
    if (n > SCAP) n = SCAP;
    const int2* base = pairs + (size_t)sp * SCAP;
    int cbase = sp * SUB_SZ;
    int ng = n >> 2;                              // groups of 4 records
    for (int i = w * 256 + threadIdx.x; i < ng; i += 8192) {
        v4i a = __builtin_nontemporal_load((const v4i*)base + 2 * i);
        v4i c = __builtin_nontemporal_load((const v4i*)base + 2 * i + 1);
        atomicAdd(&counts[cbase + ((unsigned)a.x >> 17)], 1);
        atomicAdd(&counts[cbase + ((unsigned)a.z >> 17)], 1);
        atomicAdd(&counts[cbase + ((unsigned)c.x >> 17)], 1);
        atomicAdd(&counts[cbase + ((unsigned)c.z >> 17)], 1);
    }
    if (w == 0 && threadIdx.x < 3) {
        int idx = (ng << 2) + threadIdx.x;
        if (idx < n) {
            int2 pr = base[idx];
            atomicAdd(&counts[cbase + ((unsigned)pr.x >> 17)], 1);
        }
    }
}

// ---- scan step 1 (R13) ----
__global__ __launch_bounds__(256) void scan1(const int* __restrict__ counts,
                                             int* __restrict__ offsets,
                                             int* __restrict__ blocksum) {
    __shared__ int lds[256];
    int tid = threadIdx.x;
    int base = blockIdx.x * 1024 + tid * 4;
    int c0 = (base + 0 < NNODES) ? counts[base + 0] : 0;
    int c1 = (base + 1 < NNODES) ? counts[base + 1] : 0;
    int c2 = (base + 2 < NNODES) ? counts[base + 2] : 0;
    int c3 = (base + 3 < NNODES) ? counts[base + 3] : 0;
    int t = c0 + c1 + c2 + c3;
    lds[tid] = t;
    __syncthreads();
    for (int d = 1; d < 256; d <<= 1) {
        int v = lds[tid];
        int add = (tid >= d) ? lds[tid - d] : 0;
        __syncthreads();
        lds[tid] = v + add;
        __syncthreads();
    }
    int incl = lds[tid];
    int excl = incl - t;
    if (base + 0 < NNODES) offsets[base + 0] = excl;
    if (base + 1 < NNODES) offsets[base + 1] = excl + c0;
    if (base + 2 < NNODES) offsets[base + 2] = excl + c0 + c1;
    if (base + 3 < NNODES) offsets[base + 3] = excl + c0 + c1 + c2;
    if (tid == 255) blocksum[blockIdx.x] = incl;
}

// ---- scan step 2 (R13) ----
__global__ __launch_bounds__(128) void scan2p(int* __restrict__ blocksum, int nb) {
    __shared__ int lds[128];
    int tid = threadIdx.x;
    int v = (tid < nb) ? blocksum[tid] : 0;
    lds[tid] = v;
    __syncthreads();
    for (int d = 1; d < 128; d <<= 1) {
        int x = lds[tid];
        int add = (tid >= d) ? lds[tid - d] : 0;
        __syncthreads();
        lds[tid] = x + add;
        __syncthreads();
    }
    if (tid < nb) blocksum[tid] = lds[tid] - v;   // exclusive
}

// ---- scan step 3: finalize offsets (doubles as fill cursor) (R13) ----
__global__ __launch_bounds__(256) void scan3(int* __restrict__ offsets,
                                             const int* __restrict__ blocksum) {
    int add = blocksum[blockIdx.x];
    int base = blockIdx.x * 1024 + threadIdx.x * 4;
    #pragma unroll
    for (int i = 0; i < 4; ++i) {
        int idx = base + i;
        if (idx < NNODES) offsets[idx] += add;
    }
}

// ---- pass C: fill bins per sub-part (~200KB dirty window, L2-resident) (R13) ----
__global__ __launch_bounds__(256) void fill_part2(const int2* __restrict__ pairs,
                                                  const int* __restrict__ scur,
                                                  int* __restrict__ offsets,
                                                  int2* __restrict__ bins) {
    int b = blockIdx.x;
    int sp = b & 63;
    int w = b >> 6;
    int n = scur[sp * SCUR_STRIDE];
    if (n > SCAP) n = SCAP;
    const int2* base = pairs + (size_t)sp * SCAP;
    int cbase = sp * SUB_SZ;
    int ng = n >> 2;
    for (int i = w * 256 + threadIdx.x; i < ng; i += 8192) {
        v4i a = __builtin_nontemporal_load((const v4i*)base + 2 * i);
        v4i c = __builtin_nontemporal_load((const v4i*)base + 2 * i + 1);
        int d0 = cbase + ((unsigned)a.x >> 17);
        int p0 = atomicAdd(&offsets[d0], 1);
        bins[p0] = make_int2(a.x & 0x1FFFF, a.y);
        int d1 = cbase + ((unsigned)a.z >> 17);
        int p1 = atomicAdd(&offsets[d1], 1);
        bins[p1] = make_int2(a.z & 0x1FFFF, a.w);
        int d2 = cbase + ((unsigned)c.x >> 17);
        int p2 = atomicAdd(&offsets[d2], 1);
        bins[p2] = make_int2(c.x & 0x1FFFF, c.y);
        int d3 = cbase + ((unsigned)c.z >> 17);
        int p3 = atomicAdd(&offsets[d3], 1);
        bins[p3] = make_int2(c.z & 0x1FFFF, c.w);
    }
    if (w == 0 && threadIdx.x < 3) {
        int idx = (ng << 2) + threadIdx.x;
        if (idx < n) {
            int2 pr = base[idx];
            int d = cbase + ((unsigned)pr.x >> 17);
            int p = atomicAdd(&offsets[d], 1);
            bins[p] = make_int2(pr.x & 0x1FFFF, pr.y);
        }
    }
}

// ---- pull: 16 lanes/node, uint4 gathers, 8-deep unroll for MLP ----
// offsets holds END pointer after fill; start = end - counts[v].
__global__ __launch_bounds__(256) void pull_x16(const __half* __restrict__ nf16,
                                                const int* __restrict__ offsets,
                                                const int* __restrict__ counts,
                                                const int2* __restrict__ bins,
                                                __half* __restrict__ x16) {
    int gid = blockIdx.x * 256 + threadIdx.x;
    int v = gid >> 4;
    int lane = gid & 15;
    if (v >= NNODES) return;
    int end = offsets[v];
    int start = end - counts[v];
    const uint4* nfu4 = (const uint4*)nf16;   // row = 16 uint4
    __half2 z2 = __float2half2_rn(0.f);
    U4H a0, a1, a2, a3;
    #pragma unroll
    for (int j = 0; j < 4; ++j) { a0.h[j] = z2; a1.h[j] = z2; a2.h[j] = z2; a3.h[j] = z2; }
    int k = start;
    for (; k + 8 <= end; k += 8) {
        v4i eA = __builtin_nontemporal_load((const v4i*)((const v2i*)bins + k));
        v4i eB = __builtin_nontemporal_load((const v4i*)((const v2i*)bins + k) + 1);
        v4i eC = __builtin_nontemporal_load((const v4i*)((const v2i*)bins + k) + 2);
        v4i eD = __builtin_nontemporal_load((const v4i*)((const v2i*)bins + k) + 3);
        U4H u0, u1, u2, u3, u4, u5, u6, u7;
        u0.u = nfu4[(size_t)eA.x * 16 + lane];
        u1.u = nfu4[(size_t)eA.z * 16 + lane];
        u2.u = nfu4[(size_t)eB.x * 16 + lane];
        u3.u = nfu4[(size_t)eB.z * 16 + lane];
        u4.u = nfu4[(size_t)eC.x * 16 + lane];
        u5.u = nfu4[(size_t)eC.z * 16 + lane];
        u6.u = nfu4[(size_t)eD.x * 16 + lane];
        u7.u = nfu4[(size_t)eD.z * 16 + lane];
        __half2 w0 = __float2half2_rn(__int_as_float(eA.y));
        __half2 w1 = __float2half2_rn(__int_as_float(eA.w));
        __half2 w2 = __float2half2_rn(__int_as_float(eB.y));
        __half2 w3 = __float2half2_rn(__int_as_float(eB.w));
        __half2 w4 = __float2half2_rn(__int_as_float(eC.y));
        __half2 w5 = __float2half2_rn(__int_as_float(eC.w));
        __half2 w6 = __float2half2_rn(__int_as_float(eD.y));
        __half2 w7 = __float2half2_rn(__int_as_float(eD.w));
        #pragma unroll
        for (int j = 0; j < 4; ++j) {
            a0.h[j] = __hfma2(w0, u0.h[j], a0.h[j]);
            a1.h[j] = __hfma2(w1, u1.h[j], a1.h[j]);
            a2.h[j] = __hfma2(w2, u2.h[j], a2.h[j]);
            a3.h[j] = __hfma2(w3, u3.h[j], a3.h[j]);
            a0.h[j] = __hfma2(w4, u4.h[j], a0.h[j]);
            a1.h[j] = __hfma2(w5, u5.h[j], a1.h[j]);
            a2.h[j] = __hfma2(w6, u6.h[j], a2.h[j]);
            a3.h[j] = __hfma2(w7, u7.h[j], a3.h[j]);
        }
    }
    for (; k + 4 <= end; k += 4) {
        v2i e0 = __builtin_nontemporal_load((const v2i*)bins + k);
        v2i e1 = __builtin_nontemporal_load((const v2i*)bins + k + 1);
        v2i e2 = __builtin_nontemporal_load((const v2i*)bins + k + 2);
        v2i e3 = __builtin_nontemporal_load((const v2i*)bins + k + 3);
        U4H u0, u1, u2, u3;
        u0.u = nfu4[(size_t)e0.x * 16 + lane];
        u1.u = nfu4[(size_t)e1.x * 16 + lane];
        u2.u = nfu4[(size_t)e2.x * 16 + lane];
        u3.u = nfu4[(size_t)e3.x * 16 + lane];
        __half2 w0 = __float2half2_rn(__int_as_float(e0.y));
        __half2 w1 = __float2half2_rn(__int_as_float(e1.y));
        __half2 w2 = __float2half2_rn(__int_as_float(e2.y));
        __half2 w3 = __float2half2_rn(__int_as_float(e3.y));
        #pragma unroll
        for (int j = 0; j < 4; ++j) {
            a0.h[j] = __hfma2(w0, u0.h[j], a0.h[j]);
            a1.h[j] = __hfma2(w1, u1.h[j], a1.h[j]);
            a2.h[j] = __hfma2(w2, u2.h[j], a2.h[j]);
            a3.h[j] = __hfma2(w3, u3.h[j], a3.h[j]);
        }
    }
    for (; k < end; ++k) {
        v2i e = __builtin_nontemporal_load((const v2i*)bins + k);
        U4H u; u.u = nfu4[(size_t)e.x * 16 + lane];
        __half2 w = __float2half2_rn(__int_as_float(e.y));
        #pragma unroll
        for (int j = 0; j < 4; ++j) a0.h[j] = __hfma2(w, u.h[j], a0.h[j]);
    }
    U4H s, sf;
    sf.u = nfu4[(size_t)v * 16 + lane];
    #pragma unroll
    for (int j = 0; j < 4; ++j) {
        __half2 t2 = __hadd2(__hadd2(a0.h[j], a1.h[j]), __hadd2(a2.h[j], a3.h[j]));
        s.h[j] = __hmul2(t2, sf.h[j]);
    }
    __builtin_nontemporal_store(*(v4u*)&s.u, (v4u*)x16 + (size_t)v * 16 + lane);
}

// ---- MFMA gemm: out = leaky_relu(x16 @ W16^T), W16 staged in LDS (R13-proven) ----
__global__ __launch_bounds__(256) void gemm16(const __half* __restrict__ x16,
                                              const __half* __restrict__ W16,
                                              float* __restrict__ out) {
    __shared__ _Float16 Wl[128 * 128];   // 32 KB
    __shared__ _Float16 Xl[64 * 128];    // 16 KB
    int tid = threadIdx.x;

    const v4u* Wg = (const v4u*)W16;
    for (int i = tid; i < 2048; i += 256) {
        int r = i >> 4, c = i & 15;
        v4u u = Wg[i];
        *(v4u*)&Wl[r * 128 + ((c ^ (r & 7)) << 3)] = u;
    }

    int rbase = blockIdx.x * 64;
    for (int i = tid; i < 1024; i += 256) {
        int r = i >> 4, c = i & 15;
        int grow = rbase + r;
        v4u u = (v4u){0u, 0u, 0u, 0u};
        if (grow < NNODES)
            u = __builtin_nontemporal_load((const v4u*)x16 + (size_t)grow * 16 + c);
        *(v4u*)&Xl[r * 128 + ((c ^ (r & 7)) << 3)] = u;
    }
    __syncthreads();

    int wave = tid >> 6;
    int lane = tid & 63;
    int n = lane & 15;
    int g = lane >> 4;

    v4f acc[8];
    #pragma unroll
    for (int jb = 0; jb < 8; ++jb) acc[jb] = (v4f){0.f, 0.f, 0.f, 0.f};

    #pragma unroll
    for (int kb = 0; kb < 4; ++kb) {
        v8h a = *(v8h*)&Xl[(wave * 16 + n) * 128 + (((kb * 4 + g) ^ (n & 7)) << 3)];
        #pragma unroll
        for (int jb = 0; jb < 8; ++jb) {
            v8h b = *(v8h*)&Wl[(jb * 16 + n) * 128 + (((kb * 4 + g) ^ (n & 7)) << 3)];
            acc[jb] = __builtin_amdgcn_mfma_f32_16x16x32_f16(a, b, acc[jb], 0, 0, 0);
        }
    }

    int row0 = rbase + wave * 16 + g * 4;
    #pragma unroll
    for (int jb = 0; jb < 8; ++jb) {
        #pragma unroll
        for (int reg = 0; reg < 4; ++reg) {
            int r = row0 + reg;
            if (r < NNODES) {
                float v = acc[jb][reg];
                v = v >= 0.f ? v : NEG_SLOPE * v;
                __builtin_nontemporal_store(v, out + (size_t)r * 128 + jb * 16 + n);
            }
        }
    }
}

// ---- mid path (no pairs space): direct hist + 8-part fill ----
__global__ __launch_bounds__(256) void hist_dst4(const int* __restrict__ edst,
                                                 int* __restrict__ counts) {
    int i = blockIdx.x * 256 + threadIdx.x;
    if (i < NEDGES / 4) {
        int4 d = ((const int4*)edst)[i];
        atomicAdd(&counts[d.x], 1);
        atomicAdd(&counts[d.y], 1);
        atomicAdd(&counts[d.z], 1);
        atomicAdd(&counts[d.w], 1);
    }
}

__global__ __launch_bounds__(256) void fill_part(const int* __restrict__ esrc,
                                                 const int* __restrict__ edst,
                                                 const float* __restrict__ ew,
                                                 int* __restrict__ offsets,
                                                 int2* __restrict__ bins) {
    int part = blockIdx.x & (NPART - 1);
    int lo = part * PART_SZ;
    int hi = lo + PART_SZ;
    int t = (blockIdx.x >> 3) * 256 + threadIdx.x;
    int stride = (gridDim.x >> 3) * 256;
    int nq = NEDGES / 4;
    for (int i = t; i < nq; i += stride) {
        int4 d = ((const int4*)edst)[i];
        int e = i * 4;
        if (d.x >= lo && d.x < hi) {
            int p = atomicAdd(&offsets[d.x], 1);
            bins[p] = make_int2(esrc[e + 0], __float_as_int(ew[e + 0]));
        }
        if (d.y >= lo && d.y < hi) {
            int p = atomicAdd(&offsets[d.y], 1);
            bins[p] = make_int2(esrc[e + 1], __float_as_int(ew[e + 1]));
        }
        if (d.z >= lo && d.z < hi) {
            int p = atomicAdd(&offsets[d.z], 1);
            bins[p] = make_int2(esrc[e + 2], __float_as_int(ew[e + 2]));
        }
        if (d.w >= lo && d.w < hi) {
            int p = atomicAdd(&offsets[d.w], 1);
            bins[p] = make_int2(esrc[e + 3], __float_as_int(ew[e + 3]));
        }
    }
}

// ---- pull variant for mid path: bins hold plain (src, w) ----
__global__ __launch_bounds__(256) void pull_x16_mid(const __half* __restrict__ nf16,
                                                    const int* __restrict__ offsets,
                                                    const int* __restrict__ counts,
                                                    const int2* __restrict__ bins,
                                                    __half* __restrict__ x16) {
    int gid = blockIdx.x * 256 + threadIdx.x;
    int v = gid >> 4;
    int lane = gid & 15;
    if (v >= NNODES) return;
    int end = offsets[v];
    int start = end - counts[v];
    const uint4* nfu4 = (const uint4*)nf16;
    __half2 z2 = __float2half2_rn(0.f);
    U4H a0;
    #pragma unroll
    for (int j = 0; j < 4; ++j) a0.h[j] = z2;
    for (int k = start; k < end; ++k) {
        v2i e = __builtin_nontemporal_load((const v2i*)bins + k);
        U4H u; u.u = nfu4[(size_t)e.x * 16 + lane];
        __half2 w = __float2half2_rn(__int_as_float(e.y));
        #pragma unroll
        for (int j = 0; j < 4; ++j) a0.h[j] = __hfma2(w, u.h[j], a0.h[j]);
    }
    U4H s, sf;
    sf.u = nfu4[(size_t)v * 16 + lane];
    #pragma unroll
    for (int j = 0; j < 4; ++j) s.h[j] = __hmul2(a0.h[j], sf.h[j]);
    __builtin_nontemporal_store(*(v4u*)&s.u, (v4u*)x16 + (size_t)v * 16 + lane);
}

// ---- last-resort fallback (f32, atomic scatter) ----
__global__ __launch_bounds__(256) void scatter_edges(
    const float* __restrict__ nfeat, const int* __restrict__ esrc,
    const int* __restrict__ edst, const float* __restrict__ ew,
    float* __restrict__ hn) {
    long long t = (long long)blockIdx.x * 256 + threadIdx.x;
    int e = (int)(t >> 5);
    if (e >= NEDGES) return;
    int lane = (int)(t & 31);
    int s = esrc[e];
    int d = edst[e];
    float w = ew[e];
    float4 v = ((const float4*)(nfeat + (size_t)s * DIM))[lane];
    float* o = hn + (size_t)d * DIM + lane * 4;
    unsafeAtomicAdd(o + 0, v.x * w);
    unsafeAtomicAdd(o + 1, v.y * w);
    unsafeAtomicAdd(o + 2, v.z * w);
    unsafeAtomicAdd(o + 3, v.w * w);
}

__global__ __launch_bounds__(256) void elem_mul(const float* __restrict__ nfeat,
                                                float* __restrict__ hn, int n4) {
    int i = blockIdx.x * blockDim.x + threadIdx.x;
    int stride = gridDim.x * blockDim.x;
    for (; i < n4; i += stride) {
        float4 a = ((const float4*)nfeat)[i];
        float4 b = ((float4*)hn)[i];
        b.x *= a.x; b.y *= a.y; b.z *= a.z; b.w *= a.w;
        ((float4*)hn)[i] = b;
    }
}

__global__ __launch_bounds__(256) void bi_gemm2(
    const float* __restrict__ x, const float* __restrict__ W,
    float* __restrict__ out) {
    extern __shared__ float lds[];
    float4* W4  = (float4*)lds;
    float*  xs  = lds + 128 * 128;
    float4* xs4 = (float4*)xs;
    int tid = threadIdx.x;
    const float4* Wg = (const float4*)W;
    for (int i = tid; i < 128 * 32; i += 256) {
        int j = i >> 5, d4 = i & 31;
        W4[(j << 5) | (d4 ^ ((j >> 2) & 7))] = Wg[i];
    }
    __syncthreads();
    int tx = tid & 31, ty = tid >> 5;
    int j0 = tx << 2, r0 = ty << 2;
    int ntiles = NNODES / 32;
    for (int tile = blockIdx.x; tile < ntiles; tile += gridDim.x) {
        int rbase = tile * 32;
        for (int i = tid; i < 32 * 32; i += 256)
            xs4[i] = ((const float4*)x)[(size_t)rbase * 32 + i];
        __syncthreads();
        float acc[4][4];
        #pragma unroll
        for (int r = 0; r < 4; ++r)
            #pragma unroll
            for (int j = 0; j < 4; ++j) acc[r][j] = 0.f;
        #pragma unroll 4
        for (int d4 = 0; d4 < 32; ++d4) {
            float4 xv[4], wv[4];
            #pragma unroll
            for (int r = 0; r < 4; ++r) xv[r] = xs4[((r0 + r) << 5) | d4];
            #pragma unroll
            for (int j = 0; j < 4; ++j) {
                int jj = j0 + j;
                wv[j] = W4[(jj << 5) | (d4 ^ ((jj >> 2) & 7))];
            }
            #pragma unroll
            for (int r = 0; r < 4; ++r)
                #pragma unroll
                for (int j = 0; j < 4; ++j) {
                    acc[r][j] += xv[r].x * wv[j].x;
                    acc[r][j] += xv[r].y * wv[j].y;
                    acc[r][j] += xv[r].z * wv[j].z;
                    acc[r][j] += xv[r].w * wv[j].w;
                }
        }
        __syncthreads();
        #pragma unroll
        for (int r = 0; r < 4; ++r) {
            float4 o;
            o.x = acc[r][0] >= 0.f ? acc[r][0] : NEG_SLOPE * acc[r][0];
            o.y = acc[r][1] >= 0.f ? acc[r][1] : NEG_SLOPE * acc[r][1];
            o.z = acc[r][2] >= 0.f ? acc[r][2] : NEG_SLOPE * acc[r][2];
            o.w = acc[r][3] >= 0.f ? acc[r][3] : NEG_SLOPE * acc[r][3];
            size_t row = (size_t)(rbase + r0 + r);
            ((float4*)out)[row * (DIM / 4) + tx] = o;
        }
    }
}

extern "C" void kernel_launch(void* const* d_in, const int* in_sizes, int n_in,
                              void* d_out, int out_size, void* d_ws, size_t ws_size,
                              hipStream_t stream) {
    const float* nfeat = (const float*)d_in[0];
    const int*   esrc  = (const int*)d_in[1];
    const int*   edst  = (const int*)d_in[2];
    const float* ew    = (const float*)d_in[3];
    const float* W     = (const float*)d_in[4];
    float* out = (float*)d_out;

    // ---- workspace layout ----
    size_t off = 0;
    size_t nf16_off = off;     off += align256((size_t)NNODES * DIM * 2);  // 25.6 MB
    size_t x16_off = off;      off += align256((size_t)NNODES * DIM * 2);  // 25.6 MB
    size_t w16_off = off;      off += align256((size_t)DIM * DIM * 2);     // 32 KB
    size_t cnt_off = off;      off += align256((size_t)NNODES * 4);
    size_t ofs_off = off;      off += align256((size_t)NNODES * 4);
    size_t scur_off = off;     off += align256((size_t)NSUB * SCUR_STRIDE * 4);
    size_t bsum_off = off;     off += align256((size_t)NB_SCAN * 4);
    size_t bins_off = off;     off += align256((size_t)NEDGES * 8);        // 12.8 MB
    size_t need_mid = off;
    size_t pair_off = off;     off += align256((size_t)NSUB * SCAP * 8);   // 13.8 MB
    size_t need_full = off;

    char* ws = (char*)d_ws;

    if (ws_size >= need_mid) {
        __half* nf16 = (__half*)(ws + nf16_off);
        __half* x16  = (__half*)(ws + x16_off);
        __half* W16  = (__half*)(ws + w16_off);
        int* counts = (int*)(ws + cnt_off);
        int* offsets = (int*)(ws + ofs_off);
        int* scur = (int*)(ws + scur_off);
        int* blocksum = (int*)(ws + bsum_off);
        int2* bins = (int2*)(ws + bins_off);
        int2* pairs = (int2*)(ws + pair_off);

        prep<<<2048, 256, 0, stream>>>(nfeat, W, nf16, W16, counts, scur);
        int pgrid = (NNODES * 16 + 255) / 256;   // 6250
        if (ws_size >= need_full) {
            int sgrid = (NEDGES + CHUNK - 1) / CHUNK;   // 782
            split_edges<<<sgrid, 256, 0, stream>>>(esrc, edst, ew, scur, pairs);
            hist_part<<<2048, 256, 0, stream>>>(pairs, scur, counts);
            scan1<<<NB_SCAN, 256, 0, stream>>>(counts, offsets, blocksum);
            scan2p<<<1, 128, 0, stream>>>(blocksum, NB_SCAN);
            scan3<<<NB_SCAN, 256, 0, stream>>>(offsets, blocksum);
            fill_part2<<<2048, 256, 0, stream>>>(pairs, scur, offsets, bins);
            pull_x16<<<pgrid, 256, 0, stream>>>(nf16, offsets, counts, bins, x16);
        } else {
            int e4grid = (NEDGES / 4 + 255) / 256;
            hist_dst4<<<e4grid, 256, 0, stream>>>(edst, counts);
            scan1<<<NB_SCAN, 256, 0, stream>>>(counts, offsets, blocksum);
            scan2p<<<1, 128, 0, stream>>>(blocksum, NB_SCAN);
            scan3<<<NB_SCAN, 256, 0, stream>>>(offsets, blocksum);
            fill_part<<<e4grid, 256, 0, stream>>>(esrc, edst, ew, offsets, bins);
            pull_x16_mid<<<pgrid, 256, 0, stream>>>(nf16, offsets, counts, bins, x16);
        }
        gemm16<<<GEMM_TILES, 256, 0, stream>>>(x16, W16, out);
    } else {
        // last resort: f32 atomic scatter + elementwise + VALU gemm
        float* hn = (float*)ws;
        hipFuncSetAttribute((const void*)bi_gemm2,
                            hipFuncAttributeMaxDynamicSharedMemorySize, 81920);
        zero_f32<<<2048, 256, 0, stream>>>(hn, NNODES * DIM / 4);
        int sgrid = (NEDGES * 32 + 255) / 256;
        scatter_edges<<<sgrid, 256, 0, stream>>>(nfeat, esrc, edst, ew, hn);
        elem_mul<<<2048, 256, 0, stream>>>(nfeat, hn, NNODES * DIM / 4);
        bi_gemm2<<<512, 256, 81920, stream>>>(hn, W, out);
    }
}